// Round 1
// baseline (2032.124 us; speedup 1.0000x reference)
//
#include <hip/hip_runtime.h>

#define N_MET 100000
#define N_RXN 50000
#define E_SUB 2000000
#define E_ALL 4000000
#define MSG_DIM 16
#define HIDDEN 32

// Kernel 1: per-substrate-edge message MLP (2 -> 32 tanh -> 16) + atomic
// scatter-add into h_rxn[N_RXN][MSG_DIM].
__global__ __launch_bounds__(256) void msg_scatter_kernel(
    const float* __restrict__ x_met, const float* __restrict__ sto_sub,
    const float* __restrict__ W1m, const float* __restrict__ b1m,
    const float* __restrict__ W2m, const float* __restrict__ b2m,
    const int* __restrict__ met_sub, const int* __restrict__ rxn_sub,
    float* __restrict__ h_rxn)
{
    __shared__ float sW1[2 * HIDDEN];           // W1m[0][j], W1m[1][j]
    __shared__ float sb1[HIDDEN];
    __shared__ float sW2[HIDDEN * MSG_DIM];     // W2m[j][d]
    __shared__ float sb2[MSG_DIM];
    const int t = threadIdx.x;
    if (t < 2 * HIDDEN) sW1[t] = W1m[t];
    if (t < HIDDEN)     sb1[t] = b1m[t];
    for (int i = t; i < HIDDEN * MSG_DIM; i += 256) sW2[i] = W2m[i];
    if (t < MSG_DIM)    sb2[t] = b2m[t];
    __syncthreads();

    const int e = blockIdx.x * 256 + t;
    if (e >= E_SUB) return;

    const float x = x_met[met_sub[e]];
    const float s = sto_sub[e];

    float msg[MSG_DIM];
#pragma unroll
    for (int d = 0; d < MSG_DIM; ++d) msg[d] = sb2[d];

#pragma unroll
    for (int j = 0; j < HIDDEN; ++j) {
        const float h = tanhf(x * sW1[j] + s * sW1[HIDDEN + j] + sb1[j]);
#pragma unroll
        for (int d = 0; d < MSG_DIM; ++d)
            msg[d] += h * sW2[j * MSG_DIM + d];
    }

    float* dst = h_rxn + (size_t)rxn_sub[e] * MSG_DIM;
#pragma unroll
    for (int d = 0; d < MSG_DIM; ++d)
        unsafeAtomicAdd(dst + d, msg[d]);
}

// Kernel 2: per-reaction rate MLP (16 -> 32 tanh -> 1) + softplus -> v.
__global__ __launch_bounds__(256) void rate_kernel(
    const float* __restrict__ h_rxn,
    const float* __restrict__ W1r, const float* __restrict__ b1r,
    const float* __restrict__ W2r, const float* __restrict__ b2r,
    float* __restrict__ v)
{
    __shared__ float sW1[MSG_DIM * HIDDEN];     // W1r[d][j]
    __shared__ float sb1[HIDDEN];
    __shared__ float sW2[HIDDEN];
    __shared__ float sb2;
    const int t = threadIdx.x;
    for (int i = t; i < MSG_DIM * HIDDEN; i += 256) sW1[i] = W1r[i];
    if (t < HIDDEN) { sb1[t] = b1r[t]; sW2[t] = W2r[t]; }
    if (t == 0) sb2 = b2r[0];
    __syncthreads();

    const int r = blockIdx.x * 256 + t;
    if (r >= N_RXN) return;

    float h[MSG_DIM];
#pragma unroll
    for (int d = 0; d < MSG_DIM; ++d) h[d] = h_rxn[(size_t)r * MSG_DIM + d];

    float acc = sb2;
#pragma unroll
    for (int j = 0; j < HIDDEN; ++j) {
        float z = sb1[j];
#pragma unroll
        for (int d = 0; d < MSG_DIM; ++d) z += h[d] * sW1[d * HIDDEN + j];
        acc += tanhf(z) * sW2[j];
    }
    // stable softplus: max(x,0) + log1p(exp(-|x|))
    v[r] = fmaxf(acc, 0.0f) + log1pf(expf(-fabsf(acc)));
}

// Kernel 3: per-all-edge contribution: sto_all * v[rxn_all] scattered into dxdt.
__global__ __launch_bounds__(256) void contrib_scatter_kernel(
    const float* __restrict__ sto_all, const float* __restrict__ v,
    const int* __restrict__ met_all, const int* __restrict__ rxn_all,
    float* __restrict__ dxdt)
{
    const int e = blockIdx.x * 256 + threadIdx.x;
    if (e >= E_ALL) return;
    const float c = sto_all[e] * v[rxn_all[e]];
    unsafeAtomicAdd(dxdt + met_all[e], c);
}

extern "C" void kernel_launch(void* const* d_in, const int* in_sizes, int n_in,
                              void* d_out, int out_size, void* d_ws, size_t ws_size,
                              hipStream_t stream) {
    const float* x_met   = (const float*)d_in[0];
    const float* sto_sub = (const float*)d_in[1];
    const float* sto_all = (const float*)d_in[2];
    const float* W1m     = (const float*)d_in[3];
    const float* b1m     = (const float*)d_in[4];
    const float* W2m     = (const float*)d_in[5];
    const float* b2m     = (const float*)d_in[6];
    const float* W1r     = (const float*)d_in[7];
    const float* b1r     = (const float*)d_in[8];
    const float* W2r     = (const float*)d_in[9];
    const float* b2r     = (const float*)d_in[10];
    const int*   met_sub = (const int*)d_in[11];
    const int*   rxn_sub = (const int*)d_in[12];
    const int*   met_all = (const int*)d_in[13];
    const int*   rxn_all = (const int*)d_in[14];

    float* dxdt  = (float*)d_out;            // [N_MET]
    float* v     = dxdt + N_MET;             // [N_RXN]
    float* h_rxn = (float*)d_ws;             // [N_RXN * MSG_DIM]

    // zero the atomic accumulation targets (d_out/d_ws are poisoned 0xAA)
    hipMemsetAsync(dxdt, 0, (size_t)N_MET * sizeof(float), stream);
    hipMemsetAsync(h_rxn, 0, (size_t)N_RXN * MSG_DIM * sizeof(float), stream);

    msg_scatter_kernel<<<(E_SUB + 255) / 256, 256, 0, stream>>>(
        x_met, sto_sub, W1m, b1m, W2m, b2m, met_sub, rxn_sub, h_rxn);

    rate_kernel<<<(N_RXN + 255) / 256, 256, 0, stream>>>(
        h_rxn, W1r, b1r, W2r, b2r, v);

    contrib_scatter_kernel<<<(E_ALL + 255) / 256, 256, 0, stream>>>(
        sto_all, v, met_all, rxn_all, dxdt);
}